// Round 13
// baseline (292.455 us; speedup 1.0000x reference)
//
#include <hip/hip_runtime.h>
#include <hip/hip_fp16.h>
#include <stdint.h>

// Problem constants (fixed by setup_inputs)
#define TT 2048
#define BB 64
#define VV 256
#define SS 256
#define LL 513

#define F_L2E 1.4426950408889634f
#define F_LN2 0.6931471805599453f
#define TGT_E 40   // per-lane rescale target: lane max -> [2^40, 2^41)
#define MARG  50   // max allowed C(i-1)-C(i)
#define KOFF  262144

static __device__ __forceinline__ float exp2_fast(float x) {
  float r; asm("v_exp_f32 %0, %1" : "=v"(r) : "v"(x)); return r;
}
static __device__ __forceinline__ float log2_fast(float x) {
  float r; asm("v_log_f32 %0, %1" : "=v"(r) : "v"(x)); return r;
}
static __device__ __forceinline__ void g2l16(const void* g, void* l) {
  __builtin_amdgcn_global_load_lds((const __attribute__((address_space(1))) void*)g,
                                   (__attribute__((address_space(3))) void*)l, 16, 0, 0);
}
// wave_shr:1 — lane i gets lane i-1's value; lane 0 gets 0 (bound_ctrl). Pure VALU.
static __device__ __forceinline__ float dpp_shr1_f(float x) {
  int r = __builtin_amdgcn_update_dpp(0, __float_as_int(x), 0x138, 0xF, 0xF, true);
  return __int_as_float(r);
}
static __device__ __forceinline__ int dpp_shr1_i(int x) {
  return __builtin_amdgcn_update_dpp(0, x, 0x138, 0xF, 0xF, true);
}
// wave64 inclusive MAX-scan: shr1,2,4,8 (rmask F) + bcast15 (0xa) + bcast31 (0xc)
template <int CTRL, int RMASK>
static __device__ __forceinline__ int dppmax_i(int v) {
  int d = __builtin_amdgcn_update_dpp(v, v, CTRL, RMASK, 0xF, false);
  return v > d ? v : d;
}
static __device__ __forceinline__ int scanmax_i(int v) {
  v = dppmax_i<0x111, 0xF>(v);
  v = dppmax_i<0x112, 0xF>(v);
  v = dppmax_i<0x114, 0xF>(v);
  v = dppmax_i<0x118, 0xF>(v);
  v = dppmax_i<0x142, 0xa>(v);
  v = dppmax_i<0x143, 0xc>(v);
  return v;   // inclusive prefix max per lane
}
// 2^d as f32, bit-built: exact for d in [-126,126]; 0 below; clamped above.
static __device__ __forceinline__ float pow2f(int d) {
  int dc = d > 126 ? 126 : d;
  float s = __int_as_float((dc + 127) << 23);
  return (d < -126) ? 0.f : s;
}

// ---------------------------------------------------------------------
// Phase 1: fused exp + row-sum + target-gather. (unchanged, at BW floor)
// ---------------------------------------------------------------------
__global__ __launch_bounds__(256) void k_prep2(const float* __restrict__ lp,
                                               const int* __restrict__ tgt,
                                               __half* __restrict__ Eg,
                                               float* __restrict__ Bl,
                                               float* __restrict__ D2T) {
  __shared__ int tgtl[SS];
  __shared__ __half elds[4][VV];
  int b  = blockIdx.x & (BB - 1);
  int t0 = (blockIdx.x >> 6) << 2;
  int tid = threadIdx.x;
  tgtl[tid] = tgt[b * SS + tid];
  __syncthreads();
  int w = tid >> 6, lane = tid & 63;
  int t = t0 + w;
  float4 x = reinterpret_cast<const float4*>(lp + ((size_t)t * BB + b) * VV)[lane];
  float e0 = exp2_fast(x.x * F_L2E), e1 = exp2_fast(x.y * F_L2E);
  float e2 = exp2_fast(x.z * F_L2E), e3 = exp2_fast(x.w * F_L2E);
  float z = (e0 + e1) + (e2 + e3);
  z += __shfl_xor(z, 1);
  z += __shfl_xor(z, 2);
  z += __shfl_xor(z, 4);
  z += __shfl_xor(z, 8);
  z += __shfl_xor(z, 16);
  z += __shfl_xor(z, 32);
  elds[w][4 * lane + 0] = __float2half_rn(e0);
  elds[w][4 * lane + 1] = __float2half_rn(e1);
  elds[w][4 * lane + 2] = __float2half_rn(e2);
  elds[w][4 * lane + 3] = __float2half_rn(e3);
  asm volatile("s_waitcnt lgkmcnt(0)" ::: "memory");   // wave-local write->read
  int s = 4 * lane;
  union { __half h[4]; uint2 u; } pk;
  pk.h[0] = elds[w][tgtl[s + 0]];
  pk.h[1] = elds[w][tgtl[s + 1]];
  pk.h[2] = elds[w][tgtl[s + 2]];
  pk.h[3] = elds[w][tgtl[s + 3]];
  reinterpret_cast<uint2*>(Eg + ((size_t)b * TT + t) * SS)[lane] = pk.u;
  if (lane == 0) {
    Bl[(size_t)b * TT + t]  = e0;
    D2T[(size_t)b * TT + t] = -log2_fast(z);
  }
}

// ---------------------------------------------------------------------
// Phase 2: TWO batches per wave (interleaved chains fill dependency
// stalls). Per-batch numerics = R12 verbatim (per-lane block exponent,
// margin clamp, pow2f handoff scale, libm ldexpf rescale).
// 8-step blocks, triple-buffered prefetch per batch, vmcnt(32) steady.
// ---------------------------------------------------------------------
__global__ __launch_bounds__(64) void k_ctc10(const __half* __restrict__ Eg,
                                              const float* __restrict__ Bl,
                                              const int* __restrict__ tgt,
                                              const int* __restrict__ ilen,
                                              const int* __restrict__ tlen,
                                              const float* __restrict__ D2T,
                                              float* __restrict__ lossw) {
  __shared__ float blanklds[2][TT];   // 16 KB
  __shared__ float afin[2][LL];
  __shared__ int   cfinl[2][64];
  int bA = blockIdx.x * 2, bB = bA + 1;
  int lane = threadIdx.x;
  int lenA = ilen[bA]; if (lenA > TT) lenA = TT; if (lenA < 0) lenA = 0;
  int lenB = ilen[bB]; if (lenB > TT) lenB = TT; if (lenB < 0) lenB = 0;
  int tlA  = tlen[bA]; if (tlA > SS) tlA = SS; if (tlA < 1) tlA = 1;
  int tlB  = tlen[bB]; if (tlB > SS) tlB = SS; if (tlB < 1) tlB = 1;

  const uint2* eqA = reinterpret_cast<const uint2*>(Eg) + (size_t)bA * TT * 64 + lane;
  const uint2* eqB = reinterpret_cast<const uint2*>(Eg) + (size_t)bB * TT * 64 + lane;

  int4 tvA = reinterpret_cast<const int4*>(tgt + bA * SS)[lane];
  int4 tvB = reinterpret_cast<const int4*>(tgt + bB * SS)[lane];
  int pwA = __shfl_up(tvA.w, 1), pwB = __shfl_up(tvB.w, 1);
  float mk1A = (lane > 0 && tvA.x != pwA) ? 1.f : 0.f;
  float mk3A = (tvA.y != tvA.x) ? 1.f : 0.f;
  float mk5A = (tvA.z != tvA.y) ? 1.f : 0.f;
  float mk7A = (tvA.w != tvA.z) ? 1.f : 0.f;
  float mk1B = (lane > 0 && tvB.x != pwB) ? 1.f : 0.f;
  float mk3B = (tvB.y != tvB.x) ? 1.f : 0.f;
  float mk5B = (tvB.z != tvB.y) ? 1.f : 0.f;
  float mk7B = (tvB.w != tvB.z) ? 1.f : 0.f;

  // stage both blank columns into LDS (16 g2l16 loads)
#pragma unroll
  for (int j = 0; j < 8; ++j) {
    g2l16(Bl + (size_t)bA * TT + j * 256 + lane * 4, &blanklds[0][j * 256]);
    g2l16(Bl + (size_t)bB * TT + j * 256 + lane * 4, &blanklds[1][j * 256]);
  }

  uint2 pA0[8], pA1[8], pA2[8], pB0[8], pB1[8], pB2[8];
  float aA0 = (lane == 0) ? 1.f : 0.f;
  float aA1 = 0, aA2 = 0, aA3 = 0, aA4 = 0, aA5 = 0, aA6 = 0, aA7 = 0, aA8 = 0;
  float aB0 = (lane == 0) ? 1.f : 0.f;
  float aB1 = 0, aB2 = 0, aB3 = 0, aB4 = 0, aB5 = 0, aB6 = 0, aB7 = 0, aB8 = 0;
  int   CA = 0, CB = 0;
  float sc1fA = 1.f, sc1fB = 1.f;

#define ISSUE8(S, K, TBN) do {                                                 \
    const uint2* p_ = eq##S + (size_t)(TBN) * 64;                              \
    _Pragma("unroll")                                                          \
    for (int j_ = 0; j_ < 8; ++j_) p##S##K[j_] = p_[(size_t)j_ * 64];          \
  } while (0)

#define STEP1(S, K, J) do {                                                    \
    uint2 pv = p##S##K[J];                                                     \
    float2 flo = __half22float2(*reinterpret_cast<const __half2*>(&pv.x));     \
    float2 fhi = __half22float2(*reinterpret_cast<const __half2*>(&pv.y));     \
    float pb = pb##S[J];                                                       \
    float h1 = dpp_shr1_f(a##S##7) * sc1f##S;                                  \
    a##S##8 = (a##S##8 + a##S##7) * pb;                                        \
    a##S##7 = (a##S##7 + a##S##6 + mk7##S * a##S##5) * fhi.y;                  \
    a##S##6 = (a##S##6 + a##S##5) * pb;                                        \
    a##S##5 = (a##S##5 + a##S##4 + mk5##S * a##S##3) * fhi.x;                  \
    a##S##4 = (a##S##4 + a##S##3) * pb;                                        \
    a##S##3 = (a##S##3 + a##S##2 + mk3##S * a##S##1) * flo.y;                  \
    a##S##2 = (a##S##2 + a##S##1) * pb;                                        \
    a##S##1 = (a##S##1 + a##S##0 + mk1##S * h1) * flo.x;                       \
    a##S##0 = (a##S##0 + h1) * pb;                                             \
  } while (0)

#define RESCALE1(S) do {                                                       \
    float mx = fmaxf(fmaxf(fmaxf(a##S##0, a##S##1), fmaxf(a##S##2, a##S##3)),  \
                     fmaxf(fmaxf(a##S##4, a##S##5),                            \
                           fmaxf(fmaxf(a##S##6, a##S##7), a##S##8)));          \
    bool live_ = (mx > 0.f);                                                   \
    int e_  = (int)((__float_as_uint(mx) >> 23) & 0xff);                       \
    int Cl_ = C##S + e_ - (127 + TGT_E);                                       \
    int key_ = live_ ? (Cl_ + KOFF) : 0;                                       \
    key_ = scanmax_i(key_);                                                    \
    int Cn_ = (key_ - KOFF) - MARG;                                            \
    if (live_ && Cl_ > Cn_) Cn_ = Cl_;                                         \
    int shE_ = Cn_ - C##S;                                                     \
    a##S##0 = ldexpf(a##S##0, -shE_); a##S##1 = ldexpf(a##S##1, -shE_);        \
    a##S##2 = ldexpf(a##S##2, -shE_); a##S##3 = ldexpf(a##S##3, -shE_);        \
    a##S##4 = ldexpf(a##S##4, -shE_); a##S##5 = ldexpf(a##S##5, -shE_);        \
    a##S##6 = ldexpf(a##S##6, -shE_); a##S##7 = ldexpf(a##S##7, -shE_);        \
    a##S##8 = ldexpf(a##S##8, -shE_);                                          \
    C##S = Cn_;                                                                \
    int diffi_ = dpp_shr1_i(C##S) - C##S;                                      \
    sc1f##S = pow2f(diffi_);                                                   \
  } while (0)

#define BLK(K, KN, TB, VMC) do {                                               \
    if ((VMC) == 32) { ISSUE8(A, KN, (TB) + 16); ISSUE8(B, KN, (TB) + 16); }   \
    float pbA[8], pbB[8];                                                      \
    _Pragma("unroll")                                                          \
    for (int j_ = 0; j_ < 8; ++j_) {                                           \
      pbA[j_] = blanklds[0][(TB) + j_];                                        \
      pbB[j_] = blanklds[1][(TB) + j_];                                        \
    }                                                                          \
    asm volatile("s_waitcnt vmcnt(%0)" :: "i"(VMC) : "memory");                \
    STEP1(A, K, 0); STEP1(B, K, 0); STEP1(A, K, 1); STEP1(B, K, 1);            \
    STEP1(A, K, 2); STEP1(B, K, 2); STEP1(A, K, 3); STEP1(B, K, 3);            \
    STEP1(A, K, 4); STEP1(B, K, 4); STEP1(A, K, 5); STEP1(B, K, 5);            \
    STEP1(A, K, 6); STEP1(B, K, 6); STEP1(A, K, 7); STEP1(B, K, 7);            \
    RESCALE1(A); RESCALE1(B);                                                  \
  } while (0)

  if (lenA == TT && lenB == TT) {
    ISSUE8(A, 0, 0);  ISSUE8(B, 0, 0);    // block t=0
    ISSUE8(A, 1, 8);  ISSUE8(B, 1, 8);    // block t=8
    // drain the 16 blank g2l16 loads (oldest) before first LDS reads
    asm volatile("s_waitcnt vmcnt(32)" ::: "memory");
    int t = 0;
    for (int g = 0; g < 84; ++g) {        // 84*24 = 2016
      BLK(0, 2, t, 32);
      BLK(1, 0, t + 8, 32);
      BLK(2, 1, t + 16, 32);
      t += 24;
    }
    BLK(0, 2, 2016, 32);   // issues 2032 into bank2
    BLK(1, 0, 2024, 32);   // issues 2040 into bank0
    BLK(2, 0, 2032, 16);   // no issue
    BLK(0, 0, 2040, 0);    // no issue
  } else {
    // generic fallback (len < TT): per-step loads, per-batch guards
    asm volatile("s_waitcnt vmcnt(0)" ::: "memory");
    int tmax = lenA > lenB ? lenA : lenB;
    for (int t = 0; t < tmax; ++t) {
      if (t < lenA) {
        uint2 pv = eqA[(size_t)t * 64];
        float2 flo = __half22float2(*reinterpret_cast<const __half2*>(&pv.x));
        float2 fhi = __half22float2(*reinterpret_cast<const __half2*>(&pv.y));
        float pb = blanklds[0][t];
        float h1 = dpp_shr1_f(aA7) * sc1fA;
        aA8 = (aA8 + aA7) * pb;
        aA7 = (aA7 + aA6 + mk7A * aA5) * fhi.y;
        aA6 = (aA6 + aA5) * pb;
        aA5 = (aA5 + aA4 + mk5A * aA3) * fhi.x;
        aA4 = (aA4 + aA3) * pb;
        aA3 = (aA3 + aA2 + mk3A * aA1) * flo.y;
        aA2 = (aA2 + aA1) * pb;
        aA1 = (aA1 + aA0 + mk1A * h1) * flo.x;
        aA0 = (aA0 + h1) * pb;
      }
      if (t < lenB) {
        uint2 pv = eqB[(size_t)t * 64];
        float2 flo = __half22float2(*reinterpret_cast<const __half2*>(&pv.x));
        float2 fhi = __half22float2(*reinterpret_cast<const __half2*>(&pv.y));
        float pb = blanklds[1][t];
        float h1 = dpp_shr1_f(aB7) * sc1fB;
        aB8 = (aB8 + aB7) * pb;
        aB7 = (aB7 + aB6 + mk7B * aB5) * fhi.y;
        aB6 = (aB6 + aB5) * pb;
        aB5 = (aB5 + aB4 + mk5B * aB3) * fhi.x;
        aB4 = (aB4 + aB3) * pb;
        aB3 = (aB3 + aB2 + mk3B * aB1) * flo.y;
        aB2 = (aB2 + aB1) * pb;
        aB1 = (aB1 + aB0 + mk1B * h1) * flo.x;
        aB0 = (aB0 + h1) * pb;
      }
      if (((t + 1) & 7) == 0) { RESCALE1(A); RESCALE1(B); }
    }
  }

  // normalization constants: sum of -log2(Z_t)
  float dsmA = 0.f, dsmB = 0.f;
  for (int k2 = 0; k2 < TT / 64; ++k2) {
    int t2 = lane + 64 * k2;
    if (t2 < lenA) dsmA += D2T[(size_t)bA * TT + t2];
    if (t2 < lenB) dsmB += D2T[(size_t)bB * TT + t2];
  }
#pragma unroll
  for (int sh = 1; sh < 64; sh <<= 1) {
    dsmA += __shfl_xor(dsmA, sh);
    dsmB += __shfl_xor(dsmB, sh);
  }

  afin[0][8 * lane + 0] = aA0; afin[0][8 * lane + 1] = aA1;
  afin[0][8 * lane + 2] = aA2; afin[0][8 * lane + 3] = aA3;
  afin[0][8 * lane + 4] = aA4; afin[0][8 * lane + 5] = aA5;
  afin[0][8 * lane + 6] = aA6; afin[0][8 * lane + 7] = aA7;
  afin[1][8 * lane + 0] = aB0; afin[1][8 * lane + 1] = aB1;
  afin[1][8 * lane + 2] = aB2; afin[1][8 * lane + 3] = aB3;
  afin[1][8 * lane + 4] = aB4; afin[1][8 * lane + 5] = aB5;
  afin[1][8 * lane + 6] = aB6; afin[1][8 * lane + 7] = aB7;
  if (lane == 63) { afin[0][512] = aA8; afin[1][512] = aB8; }
  cfinl[0][lane] = CA; cfinl[1][lane] = CB;
  __syncthreads();
  if (lane == 0) {
    {
      int s1 = 2 * tlA, s2 = 2 * tlA - 1;
      float v1 = afin[0][s1], v2 = afin[0][s2];
      int C1 = cfinl[0][s1 >= 512 ? 63 : (s1 >> 3)];
      int C2 = cfinl[0][s2 >= 512 ? 63 : (s2 >> 3)];
      float l1 = (v1 > 0.f) ? (log2_fast(v1) + (float)C1) : -1e30f;
      float l2 = (v2 > 0.f) ? (log2_fast(v2) + (float)C2) : -1e30f;
      float m  = fmaxf(l1, l2);
      float r  = m + log2_fast(exp2_fast(l1 - m) + exp2_fast(l2 - m));
      lossw[bA] = -F_LN2 * (r + dsmA);
    }
    {
      int s1 = 2 * tlB, s2 = 2 * tlB - 1;
      float v1 = afin[1][s1], v2 = afin[1][s2];
      int C1 = cfinl[1][s1 >= 512 ? 63 : (s1 >> 3)];
      int C2 = cfinl[1][s2 >= 512 ? 63 : (s2 >> 3)];
      float l1 = (v1 > 0.f) ? (log2_fast(v1) + (float)C1) : -1e30f;
      float l2 = (v2 > 0.f) ? (log2_fast(v2) + (float)C2) : -1e30f;
      float m  = fmaxf(l1, l2);
      float r  = m + log2_fast(exp2_fast(l1 - m) + exp2_fast(l2 - m));
      lossw[bB] = -F_LN2 * (r + dsmB);
    }
  }
#undef ISSUE8
#undef STEP1
#undef RESCALE1
#undef BLK
}

// ---------------- zero_infinity guard, /tl, mean ----------------
__global__ __launch_bounds__(64) void k_final(const float* __restrict__ lossw,
                                              const int* __restrict__ tlen,
                                              float* __restrict__ out) {
  int i = threadIdx.x;
  float v = lossw[i];
  float d = (float)tlen[i];
  v = (v < 1e29f && v > -1e30f) ? (v / d) : 0.f;
  v += __shfl_xor(v, 1);
  v += __shfl_xor(v, 2);
  v += __shfl_xor(v, 4);
  v += __shfl_xor(v, 8);
  v += __shfl_xor(v, 16);
  v += __shfl_xor(v, 32);
  if (i == 0) out[0] = v * (1.f / BB);
}

extern "C" void kernel_launch(void* const* d_in, const int* in_sizes, int n_in,
                              void* d_out, int out_size, void* d_ws, size_t ws_size,
                              hipStream_t stream) {
  const float* lp = (const float*)d_in[0];
  const int* tgt  = (const int*)d_in[1];
  const int* ilen = (const int*)d_in[2];
  const int* tlen = (const int*)d_in[3];

  size_t eg_bytes = (size_t)BB * TT * SS * 2;          // 64 MB
  __half* Eg   = (__half*)d_ws;
  float* Bl    = (float*)((char*)d_ws + eg_bytes);     // [B][T]
  float* D2T   = Bl + (size_t)BB * TT;                 // [B][T]
  float* lossw = D2T + (size_t)BB * TT;                // [B]

  k_prep2<<<BB * (TT / 4), 256, 0, stream>>>(lp, tgt, Eg, Bl, D2T);
  k_ctc10<<<BB / 2, 64, 0, stream>>>(Eg, Bl, tgt, ilen, tlen, D2T, lossw);
  k_final<<<1, 64, 0, stream>>>(lossw, tlen, (float*)d_out);
}

// Round 14
// 220.020 us; speedup vs baseline: 1.3292x; 1.3292x over previous
//
#include <hip/hip_runtime.h>
#include <hip/hip_fp16.h>
#include <stdint.h>

// Problem constants (fixed by setup_inputs)
#define TT 2048
#define BB 64
#define VV 256
#define SS 256
#define LL 513
#define CH 8          // chunk = 8 DP steps (rescale + barrier cadence)
#define NCH (TT / CH) // 256

#define F_L2E 1.4426950408889634f
#define F_LN2 0.6931471805599453f
#define TGT_E 40   // per-lane rescale target: lane max -> [2^40, 2^41)
#define MARG  50   // max allowed frame gap toward left neighbor
#define KOFF  262144

static __device__ __forceinline__ float exp2_fast(float x) {
  float r; asm("v_exp_f32 %0, %1" : "=v"(r) : "v"(x)); return r;
}
static __device__ __forceinline__ float log2_fast(float x) {
  float r; asm("v_log_f32 %0, %1" : "=v"(r) : "v"(x)); return r;
}
static __device__ __forceinline__ void g2l16(const void* g, void* l) {
  __builtin_amdgcn_global_load_lds((const __attribute__((address_space(1))) void*)g,
                                   (__attribute__((address_space(3))) void*)l, 16, 0, 0);
}
// wave_shr:1 — lane i gets lane i-1's value; lane 0 gets 0 (bound_ctrl). Pure VALU.
static __device__ __forceinline__ float dpp_shr1_f(float x) {
  int r = __builtin_amdgcn_update_dpp(0, __float_as_int(x), 0x138, 0xF, 0xF, true);
  return __int_as_float(r);
}
static __device__ __forceinline__ int dpp_shr1_i(int x) {
  return __builtin_amdgcn_update_dpp(0, x, 0x138, 0xF, 0xF, true);
}
// wave64 inclusive MAX-scan: shr1,2,4,8 (rmask F) + bcast15 (0xa) + bcast31 (0xc)
template <int CTRL, int RMASK>
static __device__ __forceinline__ int dppmax_i(int v) {
  int d = __builtin_amdgcn_update_dpp(v, v, CTRL, RMASK, 0xF, false);
  return v > d ? v : d;
}
static __device__ __forceinline__ int scanmax_i(int v) {
  v = dppmax_i<0x111, 0xF>(v);
  v = dppmax_i<0x112, 0xF>(v);
  v = dppmax_i<0x114, 0xF>(v);
  v = dppmax_i<0x118, 0xF>(v);
  v = dppmax_i<0x142, 0xa>(v);
  v = dppmax_i<0x143, 0xc>(v);
  return v;
}
// 2^d as f32, bit-built: exact for d in [-126,126]; 0 below; clamped above.
static __device__ __forceinline__ float pow2f(int d) {
  int dc = d > 126 ? 126 : d;
  float s = __int_as_float((dc + 127) << 23);
  return (d < -126) ? 0.f : s;
}

// ---------------------------------------------------------------------
// Phase 1: fused exp + row-sum + target-gather. (unchanged, at BW floor)
// ---------------------------------------------------------------------
__global__ __launch_bounds__(256) void k_prep2(const float* __restrict__ lp,
                                               const int* __restrict__ tgt,
                                               __half* __restrict__ Eg,
                                               float* __restrict__ Bl,
                                               float* __restrict__ D2T) {
  __shared__ int tgtl[SS];
  __shared__ __half elds[4][VV];
  int b  = blockIdx.x & (BB - 1);
  int t0 = (blockIdx.x >> 6) << 2;
  int tid = threadIdx.x;
  tgtl[tid] = tgt[b * SS + tid];
  __syncthreads();
  int w = tid >> 6, lane = tid & 63;
  int t = t0 + w;
  float4 x = reinterpret_cast<const float4*>(lp + ((size_t)t * BB + b) * VV)[lane];
  float e0 = exp2_fast(x.x * F_L2E), e1 = exp2_fast(x.y * F_L2E);
  float e2 = exp2_fast(x.z * F_L2E), e3 = exp2_fast(x.w * F_L2E);
  float z = (e0 + e1) + (e2 + e3);
  z += __shfl_xor(z, 1);
  z += __shfl_xor(z, 2);
  z += __shfl_xor(z, 4);
  z += __shfl_xor(z, 8);
  z += __shfl_xor(z, 16);
  z += __shfl_xor(z, 32);
  elds[w][4 * lane + 0] = __float2half_rn(e0);
  elds[w][4 * lane + 1] = __float2half_rn(e1);
  elds[w][4 * lane + 2] = __float2half_rn(e2);
  elds[w][4 * lane + 3] = __float2half_rn(e3);
  asm volatile("s_waitcnt lgkmcnt(0)" ::: "memory");
  int s = 4 * lane;
  union { __half h[4]; uint2 u; } pk;
  pk.h[0] = elds[w][tgtl[s + 0]];
  pk.h[1] = elds[w][tgtl[s + 1]];
  pk.h[2] = elds[w][tgtl[s + 2]];
  pk.h[3] = elds[w][tgtl[s + 3]];
  reinterpret_cast<uint2*>(Eg + ((size_t)b * TT + t) * SS)[lane] = pk.u;
  if (lane == 0) {
    Bl[(size_t)b * TT + t]  = e0;
    D2T[(size_t)b * TT + t] = -log2_fast(z);
  }
}

// ---------------------------------------------------------------------
// Phase 2: band split across 2 waves. Wave0 owns cells 0..255, wave1
// cells 256..512 (4/lane + top cell on tid 127). Wave1 lags by 2 chunks;
// wave0 dumps its top cell's per-step pre-values + frame C to an LDS
// ring (depth 4); wave1 consumes with exact ldexp frame adjust and seeds
// its rescale scan with wave0's C (gap <= MARG guaranteed).
// Per-wave numerics identical to the proven R12 scheme.
// ---------------------------------------------------------------------
__global__ __launch_bounds__(128) void k_ctc11(const __half* __restrict__ Eg,
                                               const float* __restrict__ Bl,
                                               const int* __restrict__ tgt,
                                               const int* __restrict__ ilen,
                                               const int* __restrict__ tlen,
                                               const float* __restrict__ D2T,
                                               float* __restrict__ lossw) {
  __shared__ float blanklds[TT];     // 8 KB
  __shared__ float bring[4][CH];     // boundary value ring
  __shared__ int   bringC[4][2];     // {frame C of values, seed key}
  __shared__ float bzero[CH];        // zeros consumed by wave0
  __shared__ int   bzeroC[2];
  __shared__ float afin[LL];
  __shared__ int   cfinl[128];

  int tid = threadIdx.x;
  int wid = tid >> 6, lane = tid & 63;
  int b = blockIdx.x;
  int len = ilen[b]; if (len > TT) len = TT; if (len < 0) len = 0;
  int tl  = tlen[b]; if (tl > SS) tl = SS; if (tl < 1) tl = 1;

  if (tid < CH) bzero[tid] = 0.f;
  if (tid < 2)  bzeroC[tid] = 0;

  if (wid == 0) {
#pragma unroll
    for (int j = 0; j < 8; ++j)
      g2l16(Bl + (size_t)b * TT + j * 256 + lane * 4, &blanklds[j * 256]);
  }

  // per-lane targets: cells base..base+3, base = wid*256 + 4*lane
  int s0 = wid * 128 + 2 * lane;      // target index of cell base+1
  int2 tv = reinterpret_cast<const int2*>(tgt + b * SS)[wid * 64 + lane];
  int pv = __shfl_up(tv.y, 1);
  if (lane == 0) pv = (s0 > 0) ? tgt[b * SS + s0 - 1] : 0;
  float mk1 = (s0 > 0 && tv.x != pv) ? 1.f : 0.f;
  float mk3 = (tv.y != tv.x) ? 1.f : 0.f;

  const unsigned* equ = reinterpret_cast<const unsigned*>(Eg)
                      + (size_t)b * TT * 128 + wid * 64 + lane;

  float b0 = (tid == 0) ? 1.f : 0.f, b1 = 0.f, b2 = 0.f, b3 = 0.f, btp = 0.f;
  int   C = 0;
  float sc1f = 1.f;
  unsigned gA[CH], gB[CH];
  float rb[CH];

  // prologue: each wave issues its own chunk-0 gather (t=0..7)
#pragma unroll
  for (int j = 0; j < CH; ++j) gA[j] = equ[(size_t)j * 128];

  asm volatile("s_waitcnt lgkmcnt(0)" ::: "memory");   // publish bzero init
  __builtin_amdgcn_s_barrier();

#define STEPW(BK, J) do {                                                      \
    rb[J] = b3;                                                                \
    unsigned pv_ = g##BK[J];                                                   \
    float2 fq = __half22float2(*reinterpret_cast<const __half2*>(&pv_));       \
    float pb = pbg[J];                                                         \
    float h1d = dpp_shr1_f(b3) * sc1f;                                         \
    float h1 = (lane == 0) ? hb[J] : h1d;                                      \
    btp = (btp + b3) * pb;                                                     \
    b3 = (b3 + b2 + mk3 * b1) * fq.y;                                          \
    b2 = (b2 + b1) * pb;                                                       \
    b1 = (b1 + b0 + mk1 * h1) * fq.x;                                          \
    b0 = (b0 + h1) * pb;                                                       \
  } while (0)

#define RESCW(BSEED) do {                                                      \
    float mx = fmaxf(fmaxf(fmaxf(b0, b1), fmaxf(b2, b3)), btp);                \
    bool live_ = (mx > 0.f);                                                   \
    int e_ = (int)((__float_as_uint(mx) >> 23) & 0xff);                        \
    int Cl_ = C + e_ - (127 + TGT_E);                                          \
    int key_ = live_ ? (Cl_ + KOFF) : 0;                                       \
    int sd_ = (lane == 0) ? (BSEED) : 0;                                       \
    key_ = key_ > sd_ ? key_ : sd_;                                            \
    key_ = scanmax_i(key_);                                                    \
    int Cn_ = (key_ - KOFF) - MARG;                                            \
    if (live_ && Cl_ > Cn_) Cn_ = Cl_;                                         \
    int shE_ = Cn_ - C;                                                        \
    b0 = ldexpf(b0, -shE_); b1 = ldexpf(b1, -shE_);                            \
    b2 = ldexpf(b2, -shE_); b3 = ldexpf(b3, -shE_);                            \
    btp = ldexpf(btp, -shE_);                                                  \
    C = Cn_;                                                                   \
    int diffi_ = dpp_shr1_i(C) - C;                                            \
    sc1f = pow2f(diffi_);                                                      \
  } while (0)

#define PROC(BKC, BKN, c_) do {                                                \
    int tb_ = (c_) * CH;                                                       \
    int tn_ = tb_ + CH; if (tn_ > TT - CH) tn_ = TT - CH;                      \
    _Pragma("unroll")                                                          \
    for (int j_ = 0; j_ < CH; ++j_) g##BKN[j_] = equ[(size_t)(tn_ + j_) * 128];\
    int sl_ = (c_) & 3;                                                        \
    const float* bv_ = wid ? &bring[sl_][0] : bzero;                           \
    const int*   bc_ = wid ? &bringC[sl_][0] : bzeroC;                         \
    int craw_ = bc_[0]; int bseed_ = bc_[1];                                   \
    int d_ = craw_ - C;                                                        \
    float hb[CH];                                                              \
    _Pragma("unroll")                                                          \
    for (int j_ = 0; j_ < CH; ++j_) hb[j_] = ldexpf(bv_[j_], d_);              \
    float pbg[CH];                                                             \
    _Pragma("unroll")                                                          \
    for (int j_ = 0; j_ < CH; ++j_) pbg[j_] = blanklds[tb_ + j_];              \
    int Cpre_ = C;                                                             \
    asm volatile("s_waitcnt vmcnt(8)" ::: "memory");                           \
    STEPW(BKC, 0); STEPW(BKC, 1); STEPW(BKC, 2); STEPW(BKC, 3);                \
    STEPW(BKC, 4); STEPW(BKC, 5); STEPW(BKC, 6); STEPW(BKC, 7);                \
    RESCW(bseed_);                                                             \
    if (wid == 0 && lane == 63) {                                              \
      int ps_ = (c_) & 3;                                                      \
      _Pragma("unroll")                                                        \
      for (int j_ = 0; j_ < CH; ++j_) bring[ps_][j_] = rb[j_];                 \
      bringC[ps_][0] = Cpre_;                                                  \
      bringC[ps_][1] = C + KOFF;                                               \
    }                                                                          \
  } while (0)

  if (len == TT) {
#pragma unroll 1
    for (int k = 0; k < NCH + 2; k += 2) {
      {
        int c = k - 2 * wid;
        if (c >= 0 && c < NCH) PROC(A, B, c);
        asm volatile("s_waitcnt lgkmcnt(0)" ::: "memory");
        __builtin_amdgcn_s_barrier();
      }
      {
        int c = k + 1 - 2 * wid;
        if (c >= 0 && c < NCH) PROC(B, A, c);
        asm volatile("s_waitcnt lgkmcnt(0)" ::: "memory");
        __builtin_amdgcn_s_barrier();
      }
    }
  } else {
    // generic path (len < TT): simple chunked loop, same protocol
    asm volatile("s_waitcnt vmcnt(0)" ::: "memory");
    int nit = (len + CH - 1) / CH + 2;
    for (int k = 0; k < nit; ++k) {
      int c = k - 2 * wid;
      int tb = c * CH;
      if (c >= 0 && tb < len) {
        int sl = c & 3;
        const float* bv_ = wid ? &bring[sl][0] : bzero;
        const int*   bc_ = wid ? &bringC[sl][0] : bzeroC;
        int craw_ = bc_[0], bseed_ = bc_[1];
        int d_ = craw_ - C;
        int Cpre_ = C;
        float rbs[CH];
        for (int j = 0; j < CH; ++j) {
          int t = tb + j;
          rbs[j] = b3;
          if (t < len) {
            unsigned pv_ = equ[(size_t)t * 128];
            float2 fq = __half22float2(*reinterpret_cast<const __half2*>(&pv_));
            float pb = blanklds[t];
            float h1d = dpp_shr1_f(b3) * sc1f;
            float h1 = (lane == 0) ? ldexpf(bv_[j], d_) : h1d;
            btp = (btp + b3) * pb;
            b3 = (b3 + b2 + mk3 * b1) * fq.y;
            b2 = (b2 + b1) * pb;
            b1 = (b1 + b0 + mk1 * h1) * fq.x;
            b0 = (b0 + h1) * pb;
          }
        }
        RESCW(bseed_);
        if (wid == 0 && lane == 63) {
          int ps = c & 3;
          for (int j = 0; j < CH; ++j) bring[ps][j] = rbs[j];
          bringC[ps][0] = Cpre_;
          bringC[ps][1] = C + KOFF;
        }
      }
      asm volatile("s_waitcnt lgkmcnt(0)" ::: "memory");
      __builtin_amdgcn_s_barrier();
    }
  }

  // normalization constant: sum of -log2(Z_t) over t < len (wave0)
  float dsm = 0.f;
  if (wid == 0) {
    for (int k2 = 0; k2 < TT / 64; ++k2) {
      int t2 = lane + 64 * k2;
      if (t2 < len) dsm += D2T[(size_t)b * TT + t2];
    }
    dsm += __shfl_xor(dsm, 1);
    dsm += __shfl_xor(dsm, 2);
    dsm += __shfl_xor(dsm, 4);
    dsm += __shfl_xor(dsm, 8);
    dsm += __shfl_xor(dsm, 16);
    dsm += __shfl_xor(dsm, 32);
  }

  int glane = wid * 64 + lane;
  afin[4 * glane + 0] = b0; afin[4 * glane + 1] = b1;
  afin[4 * glane + 2] = b2; afin[4 * glane + 3] = b3;
  if (tid == 127) afin[512] = btp;
  cfinl[glane] = C;
  __syncthreads();
  if (tid == 0) {
    int s1 = 2 * tl, s2 = 2 * tl - 1;
    float v1 = afin[s1], v2 = afin[s2];
    int C1 = cfinl[s1 >= 512 ? 127 : (s1 >> 2)];
    int C2 = cfinl[s2 >= 512 ? 127 : (s2 >> 2)];
    float l1 = (v1 > 0.f) ? (log2_fast(v1) + (float)C1) : -1e30f;
    float l2 = (v2 > 0.f) ? (log2_fast(v2) + (float)C2) : -1e30f;
    float m  = fmaxf(l1, l2);
    float r  = m + log2_fast(exp2_fast(l1 - m) + exp2_fast(l2 - m));
    lossw[b] = -F_LN2 * (r + dsm);
  }
#undef STEPW
#undef RESCW
#undef PROC
}

// ---------------- zero_infinity guard, /tl, mean ----------------
__global__ __launch_bounds__(64) void k_final(const float* __restrict__ lossw,
                                              const int* __restrict__ tlen,
                                              float* __restrict__ out) {
  int i = threadIdx.x;
  float v = lossw[i];
  float d = (float)tlen[i];
  v = (v < 1e29f && v > -1e30f) ? (v / d) : 0.f;
  v += __shfl_xor(v, 1);
  v += __shfl_xor(v, 2);
  v += __shfl_xor(v, 4);
  v += __shfl_xor(v, 8);
  v += __shfl_xor(v, 16);
  v += __shfl_xor(v, 32);
  if (i == 0) out[0] = v * (1.f / BB);
}

extern "C" void kernel_launch(void* const* d_in, const int* in_sizes, int n_in,
                              void* d_out, int out_size, void* d_ws, size_t ws_size,
                              hipStream_t stream) {
  const float* lp = (const float*)d_in[0];
  const int* tgt  = (const int*)d_in[1];
  const int* ilen = (const int*)d_in[2];
  const int* tlen = (const int*)d_in[3];

  size_t eg_bytes = (size_t)BB * TT * SS * 2;          // 64 MB
  __half* Eg   = (__half*)d_ws;
  float* Bl    = (float*)((char*)d_ws + eg_bytes);     // [B][T]
  float* D2T   = Bl + (size_t)BB * TT;                 // [B][T]
  float* lossw = D2T + (size_t)BB * TT;                // [B]

  k_prep2<<<BB * (TT / 4), 256, 0, stream>>>(lp, tgt, Eg, Bl, D2T);
  k_ctc11<<<BB, 128, 0, stream>>>(Eg, Bl, tgt, ilen, tlen, D2T, lossw);
  k_final<<<1, 64, 0, stream>>>(lossw, tlen, (float*)d_out);
}

// Round 15
// 140.914 us; speedup vs baseline: 2.0754x; 1.5614x over previous
//
#include <hip/hip_runtime.h>
#include <hip/hip_fp16.h>
#include <stdint.h>

// Problem constants (fixed by setup_inputs)
#define TT 2048
#define BB 64
#define VV 256
#define SS 256
#define LL 513

#define F_L2E 1.4426950408889634f
#define F_LN2 0.6931471805599453f
#define TGT_E 40   // per-lane rescale target: lane max -> [2^40, 2^41)
#define MARG  50   // max allowed C(i-1)-C(i)
#define KOFF  262144

typedef float f32x2 __attribute__((ext_vector_type(2)));

static __device__ __forceinline__ float exp2_fast(float x) {
  float r; asm("v_exp_f32 %0, %1" : "=v"(r) : "v"(x)); return r;
}
static __device__ __forceinline__ float log2_fast(float x) {
  float r; asm("v_log_f32 %0, %1" : "=v"(r) : "v"(x)); return r;
}
static __device__ __forceinline__ void g2l16(const void* g, void* l) {
  __builtin_amdgcn_global_load_lds((const __attribute__((address_space(1))) void*)g,
                                   (__attribute__((address_space(3))) void*)l, 16, 0, 0);
}
// wave_shr:1 — lane i gets lane i-1's value; lane 0 gets 0 (bound_ctrl). Pure VALU.
static __device__ __forceinline__ float dpp_shr1_f(float x) {
  int r = __builtin_amdgcn_update_dpp(0, __float_as_int(x), 0x138, 0xF, 0xF, true);
  return __int_as_float(r);
}
static __device__ __forceinline__ int dpp_shr1_i(int x) {
  return __builtin_amdgcn_update_dpp(0, x, 0x138, 0xF, 0xF, true);
}
// wave64 inclusive MAX-scan: shr1,2,4,8 (rmask F) + bcast15 (0xa) + bcast31 (0xc)
template <int CTRL, int RMASK>
static __device__ __forceinline__ int dppmax_i(int v) {
  int d = __builtin_amdgcn_update_dpp(v, v, CTRL, RMASK, 0xF, false);
  return v > d ? v : d;
}
static __device__ __forceinline__ int scanmax_i(int v) {
  v = dppmax_i<0x111, 0xF>(v);
  v = dppmax_i<0x112, 0xF>(v);
  v = dppmax_i<0x114, 0xF>(v);
  v = dppmax_i<0x118, 0xF>(v);
  v = dppmax_i<0x142, 0xa>(v);
  v = dppmax_i<0x143, 0xc>(v);
  return v;
}
// 2^d as f32, bit-built: exact for d in [-126,126]; 0 below; clamped above.
static __device__ __forceinline__ float pow2f(int d) {
  int dc = d > 126 ? 126 : d;
  float s = __int_as_float((dc + 127) << 23);
  return (d < -126) ? 0.f : s;
}

// ---------------------------------------------------------------------
// Phase 1: fused exp + row-sum + target-gather. (unchanged, at BW floor)
// ---------------------------------------------------------------------
__global__ __launch_bounds__(256) void k_prep2(const float* __restrict__ lp,
                                               const int* __restrict__ tgt,
                                               __half* __restrict__ Eg,
                                               float* __restrict__ Bl,
                                               float* __restrict__ D2T) {
  __shared__ int tgtl[SS];
  __shared__ __half elds[4][VV];
  int b  = blockIdx.x & (BB - 1);
  int t0 = (blockIdx.x >> 6) << 2;
  int tid = threadIdx.x;
  tgtl[tid] = tgt[b * SS + tid];
  __syncthreads();
  int w = tid >> 6, lane = tid & 63;
  int t = t0 + w;
  float4 x = reinterpret_cast<const float4*>(lp + ((size_t)t * BB + b) * VV)[lane];
  float e0 = exp2_fast(x.x * F_L2E), e1 = exp2_fast(x.y * F_L2E);
  float e2 = exp2_fast(x.z * F_L2E), e3 = exp2_fast(x.w * F_L2E);
  float z = (e0 + e1) + (e2 + e3);
  z += __shfl_xor(z, 1);
  z += __shfl_xor(z, 2);
  z += __shfl_xor(z, 4);
  z += __shfl_xor(z, 8);
  z += __shfl_xor(z, 16);
  z += __shfl_xor(z, 32);
  elds[w][4 * lane + 0] = __float2half_rn(e0);
  elds[w][4 * lane + 1] = __float2half_rn(e1);
  elds[w][4 * lane + 2] = __float2half_rn(e2);
  elds[w][4 * lane + 3] = __float2half_rn(e3);
  asm volatile("s_waitcnt lgkmcnt(0)" ::: "memory");   // wave-local write->read
  int s = 4 * lane;
  union { __half h[4]; uint2 u; } pk;
  pk.h[0] = elds[w][tgtl[s + 0]];
  pk.h[1] = elds[w][tgtl[s + 1]];
  pk.h[2] = elds[w][tgtl[s + 2]];
  pk.h[3] = elds[w][tgtl[s + 3]];
  reinterpret_cast<uint2*>(Eg + ((size_t)b * TT + t) * SS)[lane] = pk.u;
  if (lane == 0) {
    Bl[(size_t)b * TT + t]  = e0;
    D2T[(size_t)b * TT + t] = -log2_fast(z);
  }
}

// ---------------------------------------------------------------------
// Phase 2: f32 CTC DP (R12 numerics: per-lane block exponent + margin
// clamp, proven absmax 0.0). This round: cells packed in f32x2 pairs
// E={a0,a2} O={a1,a3} E2={a4,a6} O2={a5,a7} so the band update maps to
// packed VOP3P (v_pk_add/mul/fma_f32) — ~40% fewer VALU instrs/step.
// ---------------------------------------------------------------------
__global__ __launch_bounds__(64) void k_ctc12(const __half* __restrict__ Eg,
                                              const float* __restrict__ Bl,
                                              const int* __restrict__ tgt,
                                              const int* __restrict__ ilen,
                                              const int* __restrict__ tlen,
                                              const float* __restrict__ D2T,
                                              float* __restrict__ lossw) {
  __shared__ float blanklds[TT];   // 8 KB
  __shared__ float afin[LL];
  __shared__ int   cfinl[64];
  int b = blockIdx.x, lane = threadIdx.x;
  int len = ilen[b]; if (len > TT) len = TT; if (len < 0) len = 0;
  int tl  = tlen[b]; if (tl > SS) tl = SS; if (tl < 1) tl = 1;

  const float* blb = Bl  + (size_t)b * TT;
  const float* d2b = D2T + (size_t)b * TT;
  const uint2* eq  = reinterpret_cast<const uint2*>(Eg) + (size_t)b * TT * 64 + lane;

  int4 tv = reinterpret_cast<const int4*>(tgt + b * SS)[lane];
  int pw  = __shfl_up(tv.w, 1);
  f32x2 mk13 = { (lane > 0 && tv.x != pw) ? 1.f : 0.f,
                 (tv.y != tv.x) ? 1.f : 0.f };
  f32x2 mk57 = { (tv.z != tv.y) ? 1.f : 0.f,
                 (tv.w != tv.z) ? 1.f : 0.f };

  // stage blank column (8 KB) into LDS
#pragma unroll
  for (int j = 0; j < 8; ++j)
    g2l16(blb + j * 256 + lane * 4, &blanklds[j * 256]);

  uint2 pfA[16], pfB[16], pfC[16];
  // E={a0,a2} O={a1,a3} E2={a4,a6} O2={a5,a7}, a8 scalar
  f32x2 E  = { (lane == 0) ? 1.f : 0.f, 0.f };
  f32x2 O  = { 0.f, 0.f };
  f32x2 E2 = { 0.f, 0.f };
  f32x2 O2 = { 0.f, 0.f };
  float a8 = 0.f;
  int   C = 0;          // per-lane block exponent (log2 units)
  float sc1f = 1.f;     // 2^{C(lane-1)-C(lane)} (bit-built), per rescale

#define ISSUE16(BANK, TBN) do {                                                \
    const uint2* p_ = eq + (size_t)(TBN) * 64;                                 \
    _Pragma("unroll")                                                          \
    for (int j_ = 0; j_ < 16; ++j_) pf##BANK[j_] = p_[(size_t)j_ * 64];        \
  } while (0)

#define STEP32(BANK, J) do {                                                   \
    uint2 pv = pf##BANK[J];                                                    \
    float2 tlo = __half22float2(*reinterpret_cast<const __half2*>(&pv.x));     \
    float2 thi = __half22float2(*reinterpret_cast<const __half2*>(&pv.y));     \
    f32x2 flo = { tlo.x, tlo.y };                                              \
    f32x2 fhi = { thi.x, thi.y };                                              \
    float pb = pbreg[J];                                                       \
    f32x2 pbv = { pb, pb };                                                    \
    float h1 = dpp_shr1_f(O2.y) * sc1f;                                        \
    f32x2 Av = { h1,  O.x  };                                                  \
    f32x2 Bv = { O.y, O2.x };                                                  \
    float a8n  = (a8 + O2.y) * pb;                                             \
    f32x2 En   = (E  + Av) * pbv;                                              \
    f32x2 E2n  = (E2 + Bv) * pbv;                                              \
    f32x2 On   = (O  + E  + mk13 * Av) * flo;                                  \
    f32x2 O2n  = (O2 + E2 + mk57 * Bv) * fhi;                                  \
    E = En; E2 = E2n; O = On; O2 = O2n; a8 = a8n;                              \
  } while (0)

  // Per-lane rescale with margin clamp (R12 numerics verbatim).
#define RESCALE8() do {                                                        \
    float mx = fmaxf(fmaxf(fmaxf(E.x, E.y), fmaxf(O.x, O.y)),                  \
                     fmaxf(fmaxf(E2.x, E2.y),                                  \
                           fmaxf(fmaxf(O2.x, O2.y), a8)));                     \
    bool live_ = (mx > 0.f);                                                   \
    int e_  = (int)((__float_as_uint(mx) >> 23) & 0xff);                       \
    int Cl_ = C + e_ - (127 + TGT_E);                                          \
    int key_ = live_ ? (Cl_ + KOFF) : 0;                                       \
    key_ = scanmax_i(key_);                                                    \
    int Cn_ = (key_ - KOFF) - MARG;                                            \
    if (live_ && Cl_ > Cn_) Cn_ = Cl_;                                         \
    int shE_ = Cn_ - C;                                                        \
    E.x  = ldexpf(E.x, -shE_);  E.y  = ldexpf(E.y, -shE_);                     \
    O.x  = ldexpf(O.x, -shE_);  O.y  = ldexpf(O.y, -shE_);                     \
    E2.x = ldexpf(E2.x, -shE_); E2.y = ldexpf(E2.y, -shE_);                    \
    O2.x = ldexpf(O2.x, -shE_); O2.y = ldexpf(O2.y, -shE_);                    \
    a8   = ldexpf(a8, -shE_);                                                  \
    C = Cn_;                                                                   \
    int diffi_ = dpp_shr1_i(C) - C;                                            \
    sc1f = pow2f(diffi_);                                                      \
  } while (0)

#define BLK(CUR, NXT, TB, VMC) do {                                            \
    if ((VMC) == 32) ISSUE16(NXT, (TB) + 32);                                  \
    float pbreg[16];                                                           \
    _Pragma("unroll")                                                          \
    for (int j_ = 0; j_ < 16; ++j_) pbreg[j_] = blanklds[(TB) + j_];           \
    asm volatile("s_waitcnt vmcnt(%0)" :: "i"(VMC) : "memory");                \
    STEP32(CUR, 0);  STEP32(CUR, 1);  STEP32(CUR, 2);  STEP32(CUR, 3);         \
    STEP32(CUR, 4);  STEP32(CUR, 5);  STEP32(CUR, 6);  STEP32(CUR, 7);         \
    RESCALE8();                                                                \
    STEP32(CUR, 8);  STEP32(CUR, 9);  STEP32(CUR, 10); STEP32(CUR, 11);        \
    STEP32(CUR, 12); STEP32(CUR, 13); STEP32(CUR, 14); STEP32(CUR, 15);        \
    RESCALE8();                                                                \
  } while (0)

  int tcur = 0;
  if (len == TT) {
    ISSUE16(A, 0);
    ISSUE16(B, 16);
    for (int g = 0; g < 42; ++g) {
      BLK(A, C, tcur, 32);
      BLK(B, A, tcur + 16, 32);
      BLK(C, B, tcur + 32, 32);
      tcur += 48;
    }
    BLK(A, C, tcur, 16);       // tcur = 2016
    BLK(B, C, tcur + 16, 0);   // 2032
    tcur = TT;
  }

  // generic path (len < TT): plain per-step loads, same numerics
  if (tcur < len) {
    asm volatile("s_waitcnt vmcnt(0)" ::: "memory");
    while (tcur < len) {
      uint2 pv = eq[(size_t)tcur * 64];
      float2 tlo = __half22float2(*reinterpret_cast<const __half2*>(&pv.x));
      float2 thi = __half22float2(*reinterpret_cast<const __half2*>(&pv.y));
      f32x2 flo = { tlo.x, tlo.y };
      f32x2 fhi = { thi.x, thi.y };
      float pb = blanklds[tcur];
      f32x2 pbv = { pb, pb };
      float h1 = dpp_shr1_f(O2.y) * sc1f;
      f32x2 Av = { h1,  O.x  };
      f32x2 Bv = { O.y, O2.x };
      float a8n  = (a8 + O2.y) * pb;
      f32x2 En   = (E  + Av) * pbv;
      f32x2 E2n  = (E2 + Bv) * pbv;
      f32x2 On   = (O  + E  + mk13 * Av) * flo;
      f32x2 O2n  = (O2 + E2 + mk57 * Bv) * fhi;
      E = En; E2 = E2n; O = On; O2 = O2n; a8 = a8n;
      ++tcur;
      if ((tcur & 7) == 0) RESCALE8();
    }
  }

  // normalization constant: sum of -log2(Z_t) over t < len
  float dsm = 0.f;
  for (int k2 = 0; k2 < TT / 64; ++k2) {
    int t2 = lane + 64 * k2;
    if (t2 < len) dsm += d2b[t2];
  }
  dsm += __shfl_xor(dsm, 1);
  dsm += __shfl_xor(dsm, 2);
  dsm += __shfl_xor(dsm, 4);
  dsm += __shfl_xor(dsm, 8);
  dsm += __shfl_xor(dsm, 16);
  dsm += __shfl_xor(dsm, 32);

  // cells: a0=E.x a1=O.x a2=E.y a3=O.y a4=E2.x a5=O2.x a6=E2.y a7=O2.y
  afin[8 * lane + 0] = E.x;  afin[8 * lane + 1] = O.x;
  afin[8 * lane + 2] = E.y;  afin[8 * lane + 3] = O.y;
  afin[8 * lane + 4] = E2.x; afin[8 * lane + 5] = O2.x;
  afin[8 * lane + 6] = E2.y; afin[8 * lane + 7] = O2.y;
  if (lane == 63) afin[512] = a8;
  cfinl[lane] = C;
  __syncthreads();
  if (lane == 0) {
    int s1 = 2 * tl, s2 = 2 * tl - 1;
    float v1 = afin[s1], v2 = afin[s2];
    int C1 = cfinl[s1 >= 512 ? 63 : (s1 >> 3)];
    int C2 = cfinl[s2 >= 512 ? 63 : (s2 >> 3)];
    float l1 = (v1 > 0.f) ? (log2_fast(v1) + (float)C1) : -1e30f;
    float l2 = (v2 > 0.f) ? (log2_fast(v2) + (float)C2) : -1e30f;
    float m  = fmaxf(l1, l2);
    float r  = m + log2_fast(exp2_fast(l1 - m) + exp2_fast(l2 - m));
    lossw[b] = -F_LN2 * (r + dsm);
  }
#undef STEP32
#undef RESCALE8
#undef ISSUE16
#undef BLK
}

// ---------------- zero_infinity guard, /tl, mean ----------------
__global__ __launch_bounds__(64) void k_final(const float* __restrict__ lossw,
                                              const int* __restrict__ tlen,
                                              float* __restrict__ out) {
  int i = threadIdx.x;
  float v = lossw[i];
  float d = (float)tlen[i];
  v = (v < 1e29f && v > -1e30f) ? (v / d) : 0.f;
  v += __shfl_xor(v, 1);
  v += __shfl_xor(v, 2);
  v += __shfl_xor(v, 4);
  v += __shfl_xor(v, 8);
  v += __shfl_xor(v, 16);
  v += __shfl_xor(v, 32);
  if (i == 0) out[0] = v * (1.f / BB);
}

extern "C" void kernel_launch(void* const* d_in, const int* in_sizes, int n_in,
                              void* d_out, int out_size, void* d_ws, size_t ws_size,
                              hipStream_t stream) {
  const float* lp = (const float*)d_in[0];
  const int* tgt  = (const int*)d_in[1];
  const int* ilen = (const int*)d_in[2];
  const int* tlen = (const int*)d_in[3];

  size_t eg_bytes = (size_t)BB * TT * SS * 2;          // 64 MB
  __half* Eg   = (__half*)d_ws;
  float* Bl    = (float*)((char*)d_ws + eg_bytes);     // [B][T]
  float* D2T   = Bl + (size_t)BB * TT;                 // [B][T]
  float* lossw = D2T + (size_t)BB * TT;                // [B]

  k_prep2<<<BB * (TT / 4), 256, 0, stream>>>(lp, tgt, Eg, Bl, D2T);
  k_ctc12<<<BB, 64, 0, stream>>>(Eg, Bl, tgt, ilen, tlen, D2T, lossw);
  k_final<<<1, 64, 0, stream>>>(lossw, tlen, (float*)d_out);
}

// Round 16
// 136.930 us; speedup vs baseline: 2.1358x; 1.0291x over previous
//
#include <hip/hip_runtime.h>
#include <hip/hip_fp16.h>
#include <stdint.h>

// Problem constants (fixed by setup_inputs)
#define TT 2048
#define BB 64
#define VV 256
#define SS 256
#define LL 513

#define F_L2E 1.4426950408889634f
#define F_LN2 0.6931471805599453f
#define TGT_E 16   // per-lane rescale target: lane max -> [2^16, 2^17)
#define MARG  40   // max allowed C(i-1)-C(i)
#define KOFF  262144

typedef float f32x2 __attribute__((ext_vector_type(2)));

static __device__ __forceinline__ float exp2_fast(float x) {
  float r; asm("v_exp_f32 %0, %1" : "=v"(r) : "v"(x)); return r;
}
static __device__ __forceinline__ float log2_fast(float x) {
  float r; asm("v_log_f32 %0, %1" : "=v"(r) : "v"(x)); return r;
}
static __device__ __forceinline__ void g2l16(const void* g, void* l) {
  __builtin_amdgcn_global_load_lds((const __attribute__((address_space(1))) void*)g,
                                   (__attribute__((address_space(3))) void*)l, 16, 0, 0);
}
// wave_shr:1 — lane i gets lane i-1's value; lane 0 gets 0 (bound_ctrl). Pure VALU.
static __device__ __forceinline__ float dpp_shr1_f(float x) {
  int r = __builtin_amdgcn_update_dpp(0, __float_as_int(x), 0x138, 0xF, 0xF, true);
  return __int_as_float(r);
}
static __device__ __forceinline__ int dpp_shr1_i(int x) {
  return __builtin_amdgcn_update_dpp(0, x, 0x138, 0xF, 0xF, true);
}
// wave64 inclusive MAX-scan: shr1,2,4,8 (rmask F) + bcast15 (0xa) + bcast31 (0xc)
template <int CTRL, int RMASK>
static __device__ __forceinline__ int dppmax_i(int v) {
  int d = __builtin_amdgcn_update_dpp(v, v, CTRL, RMASK, 0xF, false);
  return v > d ? v : d;
}
static __device__ __forceinline__ int scanmax_i(int v) {
  v = dppmax_i<0x111, 0xF>(v);
  v = dppmax_i<0x112, 0xF>(v);
  v = dppmax_i<0x114, 0xF>(v);
  v = dppmax_i<0x118, 0xF>(v);
  v = dppmax_i<0x142, 0xa>(v);
  v = dppmax_i<0x143, 0xc>(v);
  return v;
}
// 2^d as f32, bit-built: exact for d in [-126,126]; 0 below; clamped above.
static __device__ __forceinline__ float pow2f(int d) {
  int dc = d > 126 ? 126 : d;
  float s = __int_as_float((dc + 127) << 23);
  return (d < -126) ? 0.f : s;
}

// ---------------------------------------------------------------------
// Phase 1: fused exp + row-sum + target-gather. (unchanged, at BW floor)
// ---------------------------------------------------------------------
__global__ __launch_bounds__(256) void k_prep2(const float* __restrict__ lp,
                                               const int* __restrict__ tgt,
                                               __half* __restrict__ Eg,
                                               float* __restrict__ Bl,
                                               float* __restrict__ D2T) {
  __shared__ int tgtl[SS];
  __shared__ __half elds[4][VV];
  int b  = blockIdx.x & (BB - 1);
  int t0 = (blockIdx.x >> 6) << 2;
  int tid = threadIdx.x;
  tgtl[tid] = tgt[b * SS + tid];
  __syncthreads();
  int w = tid >> 6, lane = tid & 63;
  int t = t0 + w;
  float4 x = reinterpret_cast<const float4*>(lp + ((size_t)t * BB + b) * VV)[lane];
  float e0 = exp2_fast(x.x * F_L2E), e1 = exp2_fast(x.y * F_L2E);
  float e2 = exp2_fast(x.z * F_L2E), e3 = exp2_fast(x.w * F_L2E);
  float z = (e0 + e1) + (e2 + e3);
  z += __shfl_xor(z, 1);
  z += __shfl_xor(z, 2);
  z += __shfl_xor(z, 4);
  z += __shfl_xor(z, 8);
  z += __shfl_xor(z, 16);
  z += __shfl_xor(z, 32);
  elds[w][4 * lane + 0] = __float2half_rn(e0);
  elds[w][4 * lane + 1] = __float2half_rn(e1);
  elds[w][4 * lane + 2] = __float2half_rn(e2);
  elds[w][4 * lane + 3] = __float2half_rn(e3);
  asm volatile("s_waitcnt lgkmcnt(0)" ::: "memory");   // wave-local write->read
  int s = 4 * lane;
  union { __half h[4]; uint2 u; } pk;
  pk.h[0] = elds[w][tgtl[s + 0]];
  pk.h[1] = elds[w][tgtl[s + 1]];
  pk.h[2] = elds[w][tgtl[s + 2]];
  pk.h[3] = elds[w][tgtl[s + 3]];
  reinterpret_cast<uint2*>(Eg + ((size_t)b * TT + t) * SS)[lane] = pk.u;
  if (lane == 0) {
    Bl[(size_t)b * TT + t]  = e0;
    D2T[(size_t)b * TT + t] = -log2_fast(z);
  }
}

// ---------------------------------------------------------------------
// Phase 2: f32 CTC DP, packed f32x2 cells (R15, proven absmax 0.0).
// This round: rescale cadence 8 -> 16 steps (TGT_E 16, MARG 40 re-derived
// for headroom), packed max-tree. Everything else R15 verbatim.
// ---------------------------------------------------------------------
__global__ __launch_bounds__(64) void k_ctc13(const __half* __restrict__ Eg,
                                              const float* __restrict__ Bl,
                                              const int* __restrict__ tgt,
                                              const int* __restrict__ ilen,
                                              const int* __restrict__ tlen,
                                              const float* __restrict__ D2T,
                                              float* __restrict__ lossw) {
  __shared__ float blanklds[TT];   // 8 KB
  __shared__ float afin[LL];
  __shared__ int   cfinl[64];
  int b = blockIdx.x, lane = threadIdx.x;
  int len = ilen[b]; if (len > TT) len = TT; if (len < 0) len = 0;
  int tl  = tlen[b]; if (tl > SS) tl = SS; if (tl < 1) tl = 1;

  const float* blb = Bl  + (size_t)b * TT;
  const float* d2b = D2T + (size_t)b * TT;
  const uint2* eq  = reinterpret_cast<const uint2*>(Eg) + (size_t)b * TT * 64 + lane;

  int4 tv = reinterpret_cast<const int4*>(tgt + b * SS)[lane];
  int pw  = __shfl_up(tv.w, 1);
  f32x2 mk13 = { (lane > 0 && tv.x != pw) ? 1.f : 0.f,
                 (tv.y != tv.x) ? 1.f : 0.f };
  f32x2 mk57 = { (tv.z != tv.y) ? 1.f : 0.f,
                 (tv.w != tv.z) ? 1.f : 0.f };

  // stage blank column (8 KB) into LDS
#pragma unroll
  for (int j = 0; j < 8; ++j)
    g2l16(blb + j * 256 + lane * 4, &blanklds[j * 256]);

  uint2 pfA[16], pfB[16], pfC[16];
  // E={a0,a2} O={a1,a3} E2={a4,a6} O2={a5,a7}, a8 scalar
  f32x2 E  = { (lane == 0) ? 1.f : 0.f, 0.f };
  f32x2 O  = { 0.f, 0.f };
  f32x2 E2 = { 0.f, 0.f };
  f32x2 O2 = { 0.f, 0.f };
  float a8 = 0.f;
  int   C = 0;          // per-lane block exponent (log2 units)
  float sc1f = 1.f;     // 2^{C(lane-1)-C(lane)} (bit-built), per rescale

#define ISSUE16(BANK, TBN) do {                                                \
    const uint2* p_ = eq + (size_t)(TBN) * 64;                                 \
    _Pragma("unroll")                                                          \
    for (int j_ = 0; j_ < 16; ++j_) pf##BANK[j_] = p_[(size_t)j_ * 64];        \
  } while (0)

#define STEP32(BANK, J) do {                                                   \
    uint2 pv = pf##BANK[J];                                                    \
    float2 tlo = __half22float2(*reinterpret_cast<const __half2*>(&pv.x));     \
    float2 thi = __half22float2(*reinterpret_cast<const __half2*>(&pv.y));     \
    f32x2 flo = { tlo.x, tlo.y };                                              \
    f32x2 fhi = { thi.x, thi.y };                                              \
    float pb = pbreg[J];                                                       \
    f32x2 pbv = { pb, pb };                                                    \
    float h1 = dpp_shr1_f(O2.y) * sc1f;                                        \
    f32x2 Av = { h1,  O.x  };                                                  \
    f32x2 Bv = { O.y, O2.x };                                                  \
    float a8n  = (a8 + O2.y) * pb;                                             \
    f32x2 En   = (E  + Av) * pbv;                                              \
    f32x2 E2n  = (E2 + Bv) * pbv;                                              \
    f32x2 On   = (O  + E  + mk13 * Av) * flo;                                  \
    f32x2 O2n  = (O2 + E2 + mk57 * Bv) * fhi;                                  \
    E = En; E2 = E2n; O = On; O2 = O2n; a8 = a8n;                              \
  } while (0)

  // Per-lane rescale with margin clamp; packed max-tree; 16-step cadence.
#define RESCALE16() do {                                                       \
    f32x2 m2 = __builtin_elementwise_max(__builtin_elementwise_max(E, O),      \
                                         __builtin_elementwise_max(E2, O2));   \
    float mx = fmaxf(fmaxf(m2.x, m2.y), a8);                                   \
    bool live_ = (mx > 0.f);                                                   \
    int e_  = (int)((__float_as_uint(mx) >> 23) & 0xff);                       \
    int Cl_ = C + e_ - (127 + TGT_E);                                          \
    int key_ = live_ ? (Cl_ + KOFF) : 0;                                       \
    key_ = scanmax_i(key_);                                                    \
    int Cn_ = (key_ - KOFF) - MARG;                                            \
    if (live_ && Cl_ > Cn_) Cn_ = Cl_;                                         \
    int shE_ = Cn_ - C;                                                        \
    E.x  = ldexpf(E.x, -shE_);  E.y  = ldexpf(E.y, -shE_);                     \
    O.x  = ldexpf(O.x, -shE_);  O.y  = ldexpf(O.y, -shE_);                     \
    E2.x = ldexpf(E2.x, -shE_); E2.y = ldexpf(E2.y, -shE_);                    \
    O2.x = ldexpf(O2.x, -shE_); O2.y = ldexpf(O2.y, -shE_);                    \
    a8   = ldexpf(a8, -shE_);                                                  \
    C = Cn_;                                                                   \
    int diffi_ = dpp_shr1_i(C) - C;                                            \
    sc1f = pow2f(diffi_);                                                      \
  } while (0)

#define BLK(CUR, NXT, TB, VMC) do {                                            \
    if ((VMC) == 32) ISSUE16(NXT, (TB) + 32);                                  \
    float pbreg[16];                                                           \
    _Pragma("unroll")                                                          \
    for (int j_ = 0; j_ < 16; ++j_) pbreg[j_] = blanklds[(TB) + j_];           \
    asm volatile("s_waitcnt vmcnt(%0)" :: "i"(VMC) : "memory");                \
    STEP32(CUR, 0);  STEP32(CUR, 1);  STEP32(CUR, 2);  STEP32(CUR, 3);         \
    STEP32(CUR, 4);  STEP32(CUR, 5);  STEP32(CUR, 6);  STEP32(CUR, 7);         \
    STEP32(CUR, 8);  STEP32(CUR, 9);  STEP32(CUR, 10); STEP32(CUR, 11);        \
    STEP32(CUR, 12); STEP32(CUR, 13); STEP32(CUR, 14); STEP32(CUR, 15);        \
    RESCALE16();                                                               \
  } while (0)

  int tcur = 0;
  if (len == TT) {
    ISSUE16(A, 0);
    ISSUE16(B, 16);
    for (int g = 0; g < 42; ++g) {
      BLK(A, C, tcur, 32);
      BLK(B, A, tcur + 16, 32);
      BLK(C, B, tcur + 32, 32);
      tcur += 48;
    }
    BLK(A, C, tcur, 16);       // tcur = 2016
    BLK(B, C, tcur + 16, 0);   // 2032
    tcur = TT;
  }

  // generic path (len < TT): plain per-step loads, same numerics
  if (tcur < len) {
    asm volatile("s_waitcnt vmcnt(0)" ::: "memory");
    while (tcur < len) {
      uint2 pv = eq[(size_t)tcur * 64];
      float2 tlo = __half22float2(*reinterpret_cast<const __half2*>(&pv.x));
      float2 thi = __half22float2(*reinterpret_cast<const __half2*>(&pv.y));
      f32x2 flo = { tlo.x, tlo.y };
      f32x2 fhi = { thi.x, thi.y };
      float pb = blanklds[tcur];
      f32x2 pbv = { pb, pb };
      float h1 = dpp_shr1_f(O2.y) * sc1f;
      f32x2 Av = { h1,  O.x  };
      f32x2 Bv = { O.y, O2.x };
      float a8n  = (a8 + O2.y) * pb;
      f32x2 En   = (E  + Av) * pbv;
      f32x2 E2n  = (E2 + Bv) * pbv;
      f32x2 On   = (O  + E  + mk13 * Av) * flo;
      f32x2 O2n  = (O2 + E2 + mk57 * Bv) * fhi;
      E = En; E2 = E2n; O = On; O2 = O2n; a8 = a8n;
      ++tcur;
      if ((tcur & 15) == 0) RESCALE16();
    }
  }

  // normalization constant: sum of -log2(Z_t) over t < len
  float dsm = 0.f;
  for (int k2 = 0; k2 < TT / 64; ++k2) {
    int t2 = lane + 64 * k2;
    if (t2 < len) dsm += d2b[t2];
  }
  dsm += __shfl_xor(dsm, 1);
  dsm += __shfl_xor(dsm, 2);
  dsm += __shfl_xor(dsm, 4);
  dsm += __shfl_xor(dsm, 8);
  dsm += __shfl_xor(dsm, 16);
  dsm += __shfl_xor(dsm, 32);

  // cells: a0=E.x a1=O.x a2=E.y a3=O.y a4=E2.x a5=O2.x a6=E2.y a7=O2.y
  afin[8 * lane + 0] = E.x;  afin[8 * lane + 1] = O.x;
  afin[8 * lane + 2] = E.y;  afin[8 * lane + 3] = O.y;
  afin[8 * lane + 4] = E2.x; afin[8 * lane + 5] = O2.x;
  afin[8 * lane + 6] = E2.y; afin[8 * lane + 7] = O2.y;
  if (lane == 63) afin[512] = a8;
  cfinl[lane] = C;
  __syncthreads();
  if (lane == 0) {
    int s1 = 2 * tl, s2 = 2 * tl - 1;
    float v1 = afin[s1], v2 = afin[s2];
    int C1 = cfinl[s1 >= 512 ? 63 : (s1 >> 3)];
    int C2 = cfinl[s2 >= 512 ? 63 : (s2 >> 3)];
    float l1 = (v1 > 0.f) ? (log2_fast(v1) + (float)C1) : -1e30f;
    float l2 = (v2 > 0.f) ? (log2_fast(v2) + (float)C2) : -1e30f;
    float m  = fmaxf(l1, l2);
    float r  = m + log2_fast(exp2_fast(l1 - m) + exp2_fast(l2 - m));
    lossw[b] = -F_LN2 * (r + dsm);
  }
#undef STEP32
#undef RESCALE16
#undef ISSUE16
#undef BLK
}

// ---------------- zero_infinity guard, /tl, mean ----------------
__global__ __launch_bounds__(64) void k_final(const float* __restrict__ lossw,
                                              const int* __restrict__ tlen,
                                              float* __restrict__ out) {
  int i = threadIdx.x;
  float v = lossw[i];
  float d = (float)tlen[i];
  v = (v < 1e29f && v > -1e30f) ? (v / d) : 0.f;
  v += __shfl_xor(v, 1);
  v += __shfl_xor(v, 2);
  v += __shfl_xor(v, 4);
  v += __shfl_xor(v, 8);
  v += __shfl_xor(v, 16);
  v += __shfl_xor(v, 32);
  if (i == 0) out[0] = v * (1.f / BB);
}

extern "C" void kernel_launch(void* const* d_in, const int* in_sizes, int n_in,
                              void* d_out, int out_size, void* d_ws, size_t ws_size,
                              hipStream_t stream) {
  const float* lp = (const float*)d_in[0];
  const int* tgt  = (const int*)d_in[1];
  const int* ilen = (const int*)d_in[2];
  const int* tlen = (const int*)d_in[3];

  size_t eg_bytes = (size_t)BB * TT * SS * 2;          // 64 MB
  __half* Eg   = (__half*)d_ws;
  float* Bl    = (float*)((char*)d_ws + eg_bytes);     // [B][T]
  float* D2T   = Bl + (size_t)BB * TT;                 // [B][T]
  float* lossw = D2T + (size_t)BB * TT;                // [B]

  k_prep2<<<BB * (TT / 4), 256, 0, stream>>>(lp, tgt, Eg, Bl, D2T);
  k_ctc13<<<BB, 64, 0, stream>>>(Eg, Bl, tgt, ilen, tlen, D2T, lossw);
  k_final<<<1, 64, 0, stream>>>(lossw, tlen, (float*)d_out);
}